// Round 4
// baseline (486.641 us; speedup 1.0000x reference)
//
#include <hip/hip_runtime.h>
#include <math.h>

// (B,H,L,D) = (8,8,2048,512).  rows = B*H*L = 131072, FFT length 512.
// Identity:  Re(ifft(W . fft(x))) == ifft(Wp . fft(x)),  Wp[k] = (W[k]+conj(W[(N-k)%N]))/2
// Wp Hermitian => real result for real x; map is C-linear, so two real rows sharing a
// weight row pack as z = x1 + i*x2:  ifft(Wp.fft(z)) = out1 + i*out2 exactly.
// Inverse via forward FFT:  ifft(G) = conj(fft(conj(G)))/N  (the /N is folded into Wp).
//
// R3 (resubmitted R4 after infra timeout): occupancy build. Diagnosis from R2
// counters: VALUBusy 37%, HBM 33%, Occupancy 28.5% -> latency-bound at ~2-4
// waves/SIMD. Changes:
//  - VGPR <= 64 (launch_bounds(256,8)): crosses the 64-reg occupancy step
//  - LDS 34816 -> ~22.5KB: inb staging dropped, 4KB twiddle TABLE added
//    (7 blocks/CU -> 28 waves/CU vs measured 9)
//  - twiddle table kills the per-tile twiddle_pows builds (serial cmul chains
//    + transcendentals) -> 7 conflict-free ds_read_b64 + 7 cmul per stage
//  - fine-grained grid: 16384 single-tile blocks (91% scheduling efficiency
//    vs 57% for 8 persistent blocks on 7 resident slots)
//  - plain global->VGPR input loads; TLP (not DMA pipelining) hides latency

#define HL 16384

__device__ __forceinline__ float2 cadd(float2 a, float2 b){ return make_float2(a.x+b.x, a.y+b.y); }
__device__ __forceinline__ float2 csub(float2 a, float2 b){ return make_float2(a.x-b.x, a.y-b.y); }
__device__ __forceinline__ float2 cmul(float2 a, float2 b){ return make_float2(a.x*b.x - a.y*b.y, a.x*b.y + a.y*b.x); }

// exp(-2*pi*i*f), f in revolutions. v_sin_f32/v_cos_f32 take revolutions -> 1 inst each.
__device__ __forceinline__ float2 twiddle(float f) {
    return make_float2(__builtin_amdgcn_cosf(f), -__builtin_amdgcn_sinf(f));
}

// Wave-level LDS ordering: scratch is private to the wave, so no block barrier needed.
__device__ __forceinline__ void wave_lds_fence() {
    asm volatile("s_waitcnt lgkmcnt(0)" ::: "memory");
    __builtin_amdgcn_wave_barrier();
}

// 8-point DFT, natural order, forward sign.
__device__ __forceinline__ void fft8(float2 x[8]) {
    const float c = 0.70710678118654752f;
    float2 u0 = cadd(x[0], x[4]);
    float2 u1 = cadd(x[1], x[5]);
    float2 u2 = cadd(x[2], x[6]);
    float2 u3 = cadd(x[3], x[7]);
    float2 v0 = csub(x[0], x[4]);
    float2 t1 = csub(x[1], x[5]);
    float2 t2 = csub(x[2], x[6]);
    float2 t3 = csub(x[3], x[7]);
    float2 v1 = make_float2(c*(t1.x + t1.y), c*(t1.y - t1.x));   // * W8^1
    float2 v2 = make_float2(t2.y, -t2.x);                        // * W8^2
    float2 v3 = make_float2(c*(t3.y - t3.x), -c*(t3.x + t3.y));  // * W8^3
    float2 p0 = cadd(u0, u2), p1 = cadd(u1, u3);
    float2 q0 = csub(u0, u2), q1t = csub(u1, u3);
    float2 q1 = make_float2(q1t.y, -q1t.x);
    x[0] = cadd(p0, p1);
    x[4] = csub(p0, p1);
    x[2] = cadd(q0, q1);
    x[6] = csub(q0, q1);
    float2 r0 = cadd(v0, v2), r1 = cadd(v1, v3);
    float2 s0 = csub(v0, v2), s1t = csub(v1, v3);
    float2 s1 = make_float2(s1t.y, -s1t.x);
    x[1] = cadd(r0, r1);
    x[5] = csub(r0, r1);
    x[3] = cadd(s0, s1);
    x[7] = csub(s0, s1);
}

// 512-pt forward FFT, one wave, 8 complex per lane, AoS float2 scratch (8*72 per wave).
// Twiddles come from LDS tables (built once per block):
//   twA[role][k-1] = exp(-2*pi*i*role*k/512), k=1..7   (stage 1, role in [0,64))
//   twB[m2][j-1]   = exp(-2*pi*i*m2*j/64),   j=1..7   (stage 2, m2 = lane&7)
// Table A reads: addr stride 7 float2 = 14 banks, gcd(14,32)=2 -> 4 lanes/bank (min).
// Table B reads: 8 distinct addrs on distinct banks, 8-lane broadcast each (free).
// Input: lane with role r holds z[64*j + r] in v[j].
// Output: lane holds Z[ds(lane) + 64*j] in v[j], ds(r) = ((r&7)<<3)|(r>>3).
// All sc patterns spread exactly 4 lanes/bank (b64) = bandwidth minimum.
__device__ __forceinline__ void fft512_t(float2 v[8], int role, int lane, float2* sc,
                                         const float2* __restrict__ twA,
                                         const float2* __restrict__ twB)
{
    // ---- stage 1: radix-8 over stride 64, twiddle W512^{role*k1} ----
    fft8(v);
    #pragma unroll
    for (int k = 1; k < 8; ++k) v[k] = cmul(v[k], twA[role*7 + (k-1)]);
    wave_lds_fence();                // WAR: prior reads of scratch drained
    #pragma unroll
    for (int k1 = 0; k1 < 8; ++k1) sc[k1*72 + role] = v[k1];
    wave_lds_fence();
    // ---- stage 2: 8 independent 64-pt FFTs; radix-8 over stride 8 ----
    const int k1 = lane >> 3, m2 = lane & 7;
    float2 u[8];
    #pragma unroll
    for (int m1 = 0; m1 < 8; ++m1) u[m1] = sc[k1*72 + 8*m1 + m2];
    fft8(u);
    #pragma unroll
    for (int j = 1; j < 8; ++j) u[j] = cmul(u[j], twB[m2*7 + (j-1)]);
    wave_lds_fence();                // WAR: stage-2 reads done before overwrite
    #pragma unroll
    for (int j1 = 0; j1 < 8; ++j1) sc[k1*72 + 9*j1 + m2] = u[j1];
    wave_lds_fence();
    // ---- stage 3: radix-8 over stride 1, no twiddle ----
    const int j1 = lane & 7;
    #pragma unroll
    for (int m = 0; m < 8; ++m) v[m] = sc[k1*72 + 9*j1 + m];
    fft8(v);                         // v[j2] = X[k1 + 8*j1 + 64*j2]
}

__global__ __launch_bounds__(256, 8) void sgn_fft_occ(
    const float* __restrict__ x,
    const float* __restrict__ cw,    // (H,L,512,2)
    float* __restrict__ out)
{
    __shared__ __align__(16) float2 sc[4][8*72];   // per-wave FFT scratch (18432 B)
    __shared__ __align__(16) float2 twA[64*7];     // stage-1 twiddles (3584 B)
    __shared__ __align__(16) float2 twB[8*7];      // stage-2 twiddles (448 B)

    const int tid  = threadIdx.x;
    const int wid  = tid >> 6;       // wave id in [0,4): packed pair (batches wid, wid+4)
    const int lane = tid & 63;
    const int dsl  = ((lane & 7) << 3) | (lane >> 3);
    const int hl   = blockIdx.x;     // weight row, shared by all 4 waves

    // ---- build twiddle tables (once per block, ~2 trans/thread) ----
    {
        const int role = tid & 63, j = tid >> 6;     // j in [0,4)
        twA[role*7 + 2*j] = twiddle((float)(role*(2*j+1)) * (1.0f/512.0f));
        if (j < 3)
            twA[role*7 + 2*j + 1] = twiddle((float)(role*(2*j+2)) * (1.0f/512.0f));
        if (tid < 56) {
            const int m2 = tid / 7, k = tid % 7 + 1;
            twB[m2*7 + (k-1)] = twiddle((float)(m2*k) * (1.0f/64.0f));
        }
    }
    __syncthreads();

    const int r1 = (wid       * HL + hl) * 512;   // batch wid
    const int r2 = ((wid + 4) * HL + hl) * 512;   // batch wid+4
    const float2* __restrict__ cw2 = (const float2*)cw;
    const int wrow = hl * 512;
    float2* scw = &sc[wid][0];

    // pack: z = x1 + i*x2, lane r holds z[64j + r]; coalesced 256B/instr
    float2 v[8];
    #pragma unroll
    for (int j = 0; j < 8; ++j) {
        v[j].x = x[r1 + 64*j + lane];
        v[j].y = x[r2 + 64*j + lane];
    }

    fft512_t(v, lane, lane, scw, twA, twB);

    // gate: G = Wp * Z (Wp pre-scaled by 1/512), then conj for inverse-via-forward
    const float hs = 0.5f / 512.0f;
    #pragma unroll
    for (int j2 = 0; j2 < 8; ++j2) {
        const int k  = dsl + 64*j2;
        const int nk = (512 - k) & 511;
        const float2 wk  = cw2[wrow + k];
        const float2 wnk = cw2[wrow + nk];   // same 4KB row -> L1 hit
        const float2 wp  = make_float2(hs*(wk.x + wnk.x), hs*(wk.y - wnk.y));
        const float2 g   = cmul(wp, v[j2]);
        v[j2] = make_float2(g.x, -g.y);
    }

    fft512_t(v, dsl, lane, scw, twA, twB);

    // Y = fft(conj(G)); out1 = Re(Y), out2 = -Im(Y) at k = ds(lane)+64*j2
    #pragma unroll
    for (int j2 = 0; j2 < 8; ++j2) {
        const int k = dsl + 64*j2;
        out[r1 + k] =  v[j2].x;
        out[r2 + k] = -v[j2].y;
    }
}

extern "C" void kernel_launch(void* const* d_in, const int* in_sizes, int n_in,
                              void* d_out, int out_size, void* d_ws, size_t ws_size,
                              hipStream_t stream) {
    const float* x  = (const float*)d_in[0];   // (B,H,L,D) fp32
    // d_in[1] = mask, unused
    const float* cw = (const float*)d_in[2];   // (H,L,D,2) fp32
    float* out = (float*)d_out;

    sgn_fft_occ<<<dim3(HL), dim3(256), 0, stream>>>(x, cw, out);
}

// Round 5
// 483.224 us; speedup vs baseline: 1.0071x; 1.0071x over previous
//
#include <hip/hip_runtime.h>
#include <math.h>

// (B,H,L,D) = (8,8,2048,512).  rows = B*H*L = 131072, FFT length 512.
// Identity:  Re(ifft(W . fft(x))) == ifft(Wp . fft(x)),  Wp[k] = (W[k]+conj(W[(N-k)%N]))/2
// Wp Hermitian => real result for real x; map is C-linear, so two real rows sharing a
// weight row pack as z = x1 + i*x2:  ifft(Wp.fft(z)) = out1 + i*out2 exactly.
// Inverse via forward FFT:  ifft(G) = conj(fft(conj(G)))/N  (the /N is folded into Wp).
//
// R5: kill per-tile serial stalls. R4 counters: occupancy 67% (fixed) but
// VALUBusy still 41%, dur flat -> waves stall on the 8 explicit
// s_waitcnt lgkmcnt(0) drains per tile, not on wave shortage.
// LDS (DS) ops from one wave complete IN ORDER (lgkmcnt is in-order for LDS),
// so same-wave write->read RAW and read->overwrite WAR need NO runtime wait;
// only the compiler's fine-grained lgkmcnt(N) before VALU use is required.
//  - wave_lds_fence -> compile-time wave_barrier only (0 runtime drains/tile,
//    and no "memory" clobber -> cw gate loads hoistable above FFT1)
//  - stage-2 twiddles (depend on lane&7 only, same for both calls) in 7 regs
//    built once per kernel: -14 ds_reads/tile, twB table gone

#define HL 16384

__device__ __forceinline__ float2 cadd(float2 a, float2 b){ return make_float2(a.x+b.x, a.y+b.y); }
__device__ __forceinline__ float2 csub(float2 a, float2 b){ return make_float2(a.x-b.x, a.y-b.y); }
__device__ __forceinline__ float2 cmul(float2 a, float2 b){ return make_float2(a.x*b.x - a.y*b.y, a.x*b.y + a.y*b.x); }

// exp(-2*pi*i*f), f in revolutions. v_sin_f32/v_cos_f32 take revolutions -> 1 inst each.
__device__ __forceinline__ float2 twiddle(float f) {
    return make_float2(__builtin_amdgcn_cosf(f), -__builtin_amdgcn_sinf(f));
}

// Compile-time ordering point only. Runtime ordering of same-wave DS ops is
// guaranteed by the in-order LDS pipe; C-level ordering is guaranteed because
// the lane-dependent LDS indices may-alias (compiler cannot reorder them).
__device__ __forceinline__ void lds_order() {
    __builtin_amdgcn_wave_barrier();
}

// 8-point DFT, natural order, forward sign.
__device__ __forceinline__ void fft8(float2 x[8]) {
    const float c = 0.70710678118654752f;
    float2 u0 = cadd(x[0], x[4]);
    float2 u1 = cadd(x[1], x[5]);
    float2 u2 = cadd(x[2], x[6]);
    float2 u3 = cadd(x[3], x[7]);
    float2 v0 = csub(x[0], x[4]);
    float2 t1 = csub(x[1], x[5]);
    float2 t2 = csub(x[2], x[6]);
    float2 t3 = csub(x[3], x[7]);
    float2 v1 = make_float2(c*(t1.x + t1.y), c*(t1.y - t1.x));   // * W8^1
    float2 v2 = make_float2(t2.y, -t2.x);                        // * W8^2
    float2 v3 = make_float2(c*(t3.y - t3.x), -c*(t3.x + t3.y));  // * W8^3
    float2 p0 = cadd(u0, u2), p1 = cadd(u1, u3);
    float2 q0 = csub(u0, u2), q1t = csub(u1, u3);
    float2 q1 = make_float2(q1t.y, -q1t.x);
    x[0] = cadd(p0, p1);
    x[4] = csub(p0, p1);
    x[2] = cadd(q0, q1);
    x[6] = csub(q0, q1);
    float2 r0 = cadd(v0, v2), r1 = cadd(v1, v3);
    float2 s0 = csub(v0, v2), s1t = csub(v1, v3);
    float2 s1 = make_float2(s1t.y, -s1t.x);
    x[1] = cadd(r0, r1);
    x[5] = csub(r0, r1);
    x[3] = cadd(s0, s1);
    x[7] = csub(s0, s1);
}

// 512-pt forward FFT, one wave, 8 complex per lane, AoS float2 scratch (8*72 per wave).
// Stage-1 twiddles from LDS table twA[role][k-1] = exp(-2*pi*i*role*k/512)
//   (read stride 7 float2 = 14 banks, gcd(14,32)=2 -> 4 accesses/bank = b64 minimum).
// Stage-2 twiddles from registers tw2[j] = exp(-2*pi*i*(lane&7)*j/64) (caller-built).
// Input: lane with role r holds z[64*j + r] in v[j].
// Output: lane holds Z[ds(lane) + 64*j] in v[j], ds(r) = ((r&7)<<3)|(r>>3).
// All sc patterns spread exactly 4 lanes/bank (b64) = bandwidth minimum.
__device__ __forceinline__ void fft512_t(float2 v[8], int role, int lane, float2* sc,
                                         const float2* __restrict__ twA,
                                         const float2 tw2[8])
{
    // ---- stage 1: radix-8 over stride 64, twiddle W512^{role*k1} ----
    fft8(v);
    #pragma unroll
    for (int k = 1; k < 8; ++k) v[k] = cmul(v[k], twA[role*7 + (k-1)]);
    lds_order();
    #pragma unroll
    for (int k1 = 0; k1 < 8; ++k1) sc[k1*72 + role] = v[k1];
    lds_order();
    // ---- stage 2: 8 independent 64-pt FFTs; radix-8 over stride 8 ----
    const int k1 = lane >> 3, m2 = lane & 7;
    float2 u[8];
    #pragma unroll
    for (int m1 = 0; m1 < 8; ++m1) u[m1] = sc[k1*72 + 8*m1 + m2];
    fft8(u);
    #pragma unroll
    for (int j = 1; j < 8; ++j) u[j] = cmul(u[j], tw2[j]);
    lds_order();
    #pragma unroll
    for (int j1 = 0; j1 < 8; ++j1) sc[k1*72 + 9*j1 + m2] = u[j1];
    lds_order();
    // ---- stage 3: radix-8 over stride 1, no twiddle ----
    const int j1 = lane & 7;
    #pragma unroll
    for (int m = 0; m < 8; ++m) v[m] = sc[k1*72 + 9*j1 + m];
    fft8(v);                         // v[j2] = X[k1 + 8*j1 + 64*j2]
}

__global__ __launch_bounds__(256, 8) void sgn_fft_nof(
    const float* __restrict__ x,
    const float* __restrict__ cw,    // (H,L,512,2)
    float* __restrict__ out)
{
    __shared__ __align__(16) float2 sc[4][8*72];   // per-wave FFT scratch (18432 B)
    __shared__ __align__(16) float2 twA[64*7];     // stage-1 twiddles (3584 B)

    const int tid  = threadIdx.x;
    const int wid  = tid >> 6;       // wave id in [0,4): packed pair (batches wid, wid+4)
    const int lane = tid & 63;
    const int dsl  = ((lane & 7) << 3) | (lane >> 3);
    const int hl   = blockIdx.x;     // weight row, shared by all 4 waves

    // ---- build stage-1 twiddle table (once per block, ~2 trans/thread) ----
    {
        const int role = tid & 63, j = tid >> 6;     // j in [0,4)
        twA[role*7 + 2*j] = twiddle((float)(role*(2*j+1)) * (1.0f/512.0f));
        if (j < 3)
            twA[role*7 + 2*j + 1] = twiddle((float)(role*(2*j+2)) * (1.0f/512.0f));
    }

    // ---- stage-2 twiddles in registers: depend on lane&7 only, shared by
    //      both fft512 calls (role differs, m2 doesn't). 14 VGPRs. ----
    float2 tw2[8];
    {
        const int m2 = lane & 7;
        tw2[1] = twiddle((float)m2 * (1.0f/64.0f));
        tw2[2] = cmul(tw2[1], tw2[1]);
        tw2[3] = cmul(tw2[1], tw2[2]);
        tw2[4] = cmul(tw2[2], tw2[2]);
        tw2[5] = cmul(tw2[1], tw2[4]);
        tw2[6] = cmul(tw2[2], tw2[4]);
        tw2[7] = cmul(tw2[3], tw2[4]);
    }
    __syncthreads();                 // twA visible to all waves (once per kernel)

    const int r1 = (wid       * HL + hl) * 512;   // batch wid
    const int r2 = ((wid + 4) * HL + hl) * 512;   // batch wid+4
    const float2* __restrict__ cw2 = (const float2*)cw;
    const int wrow = hl * 512;
    float2* scw = &sc[wid][0];

    // pack: z = x1 + i*x2, lane r holds z[64j + r]; coalesced 256B/instr
    float2 v[8];
    #pragma unroll
    for (int j = 0; j < 8; ++j) {
        v[j].x = x[r1 + 64*j + lane];
        v[j].y = x[r2 + 64*j + lane];
    }

    fft512_t(v, lane, lane, scw, twA, tw2);

    // gate: G = Wp * Z (Wp pre-scaled by 1/512), then conj for inverse-via-forward.
    // No "memory" clobbers anywhere -> compiler is free to hoist these cw loads
    // above FFT1 (automatic prefetch).
    const float hs = 0.5f / 512.0f;
    #pragma unroll
    for (int j2 = 0; j2 < 8; ++j2) {
        const int k  = dsl + 64*j2;
        const int nk = (512 - k) & 511;
        const float2 wk  = cw2[wrow + k];
        const float2 wnk = cw2[wrow + nk];   // same 4KB row -> L1 hit
        const float2 wp  = make_float2(hs*(wk.x + wnk.x), hs*(wk.y - wnk.y));
        const float2 g   = cmul(wp, v[j2]);
        v[j2] = make_float2(g.x, -g.y);
    }

    fft512_t(v, dsl, lane, scw, twA, tw2);

    // Y = fft(conj(G)); out1 = Re(Y), out2 = -Im(Y) at k = ds(lane)+64*j2
    #pragma unroll
    for (int j2 = 0; j2 < 8; ++j2) {
        const int k = dsl + 64*j2;
        out[r1 + k] =  v[j2].x;
        out[r2 + k] = -v[j2].y;
    }
}

extern "C" void kernel_launch(void* const* d_in, const int* in_sizes, int n_in,
                              void* d_out, int out_size, void* d_ws, size_t ws_size,
                              hipStream_t stream) {
    const float* x  = (const float*)d_in[0];   // (B,H,L,D) fp32
    // d_in[1] = mask, unused
    const float* cw = (const float*)d_in[2];   // (H,L,D,2) fp32
    float* out = (float*)d_out;

    sgn_fft_nof<<<dim3(HL), dim3(256), 0, stream>>>(x, cw, out);
}

// Round 7
// 473.811 us; speedup vs baseline: 1.0271x; 1.0199x over previous
//
#include <hip/hip_runtime.h>
#include <math.h>

// (B,H,L,D) = (8,8,2048,512).  rows = B*H*L = 131072, FFT length 512.
// Identity:  Re(ifft(W . fft(x))) == ifft(Wp . fft(x)),  Wp[k] = (W[k]+conj(W[(N-k)%N]))/2
// Wp Hermitian => real result for real x; map is C-linear, so two real rows sharing a
// weight row pack as z = x1 + i*x2:  ifft(Wp.fft(z)) = out1 + i*out2 exactly.
// Inverse via forward FFT:  ifft(G) = conj(fft(conj(G)))/N  (the /N is folded into Wp).
//
// R6 (resubmitted R7 after infra timeout): memory request-structure build.
// Evidence: six structurally different kernels (occupancy 28/54/67%,
// fences/no fences, DMA/no DMA) ALL land at 164-170us with HBM pinned at
// 2.6 TB/s -- per-CU outstanding-request limit, not occupancy/fences/VALU.
// Fix all three streams' granularity:
//  - x: 16 dword loads -> 4 dwordx4 (float4), restaged via idle sc scratch
//  - cw: 16 mid-tile cold-HBM loads -> 4 global_load_lds (1KB/op) issued as
//    the FIRST instructions; land during FFT1; gate reads become LDS reads
//  - out: 16 dword stores -> 4 dwordx4 via output restage through sc
//  per tile: 48 small VMEM ops -> 12 wide (1KB/wave-op each)

#define HL 16384

__device__ __forceinline__ float2 cadd(float2 a, float2 b){ return make_float2(a.x+b.x, a.y+b.y); }
__device__ __forceinline__ float2 csub(float2 a, float2 b){ return make_float2(a.x-b.x, a.y-b.y); }
__device__ __forceinline__ float2 cmul(float2 a, float2 b){ return make_float2(a.x*b.x - a.y*b.y, a.x*b.y + a.y*b.x); }

// exp(-2*pi*i*f), f in revolutions. v_sin_f32/v_cos_f32 take revolutions -> 1 inst each.
__device__ __forceinline__ float2 twiddle(float f) {
    return make_float2(__builtin_amdgcn_cosf(f), -__builtin_amdgcn_sinf(f));
}

// Compile-time ordering point only; same-wave DS ops complete in order.
__device__ __forceinline__ void lds_order() {
    __builtin_amdgcn_wave_barrier();
}

// 8-point DFT, natural order, forward sign.
__device__ __forceinline__ void fft8(float2 x[8]) {
    const float c = 0.70710678118654752f;
    float2 u0 = cadd(x[0], x[4]);
    float2 u1 = cadd(x[1], x[5]);
    float2 u2 = cadd(x[2], x[6]);
    float2 u3 = cadd(x[3], x[7]);
    float2 v0 = csub(x[0], x[4]);
    float2 t1 = csub(x[1], x[5]);
    float2 t2 = csub(x[2], x[6]);
    float2 t3 = csub(x[3], x[7]);
    float2 v1 = make_float2(c*(t1.x + t1.y), c*(t1.y - t1.x));   // * W8^1
    float2 v2 = make_float2(t2.y, -t2.x);                        // * W8^2
    float2 v3 = make_float2(c*(t3.y - t3.x), -c*(t3.x + t3.y));  // * W8^3
    float2 p0 = cadd(u0, u2), p1 = cadd(u1, u3);
    float2 q0 = csub(u0, u2), q1t = csub(u1, u3);
    float2 q1 = make_float2(q1t.y, -q1t.x);
    x[0] = cadd(p0, p1);
    x[4] = csub(p0, p1);
    x[2] = cadd(q0, q1);
    x[6] = csub(q0, q1);
    float2 r0 = cadd(v0, v2), r1 = cadd(v1, v3);
    float2 s0 = csub(v0, v2), s1t = csub(v1, v3);
    float2 s1 = make_float2(s1t.y, -s1t.x);
    x[1] = cadd(r0, r1);
    x[5] = csub(r0, r1);
    x[3] = cadd(s0, s1);
    x[7] = csub(s0, s1);
}

// 512-pt forward FFT, one wave, 8 complex per lane, AoS float2 scratch (8*72 per wave).
// Stage-1 twiddles: LDS table twA[role][k-1] (stride-7 float2 reads, 4/bank = min).
// Stage-2 twiddles: registers tw2[j] (function of lane&7, shared by both calls).
// Input: lane with role r holds z[64*j + r] in v[j].
// Output: lane holds Z[ds(lane) + 64*j] in v[j], ds(r) = ((r&7)<<3)|(r>>3).
__device__ __forceinline__ void fft512_t(float2 v[8], int role, int lane, float2* sc,
                                         const float2* __restrict__ twA,
                                         const float2 tw2[8])
{
    // ---- stage 1: radix-8 over stride 64, twiddle W512^{role*k1} ----
    fft8(v);
    #pragma unroll
    for (int k = 1; k < 8; ++k) v[k] = cmul(v[k], twA[role*7 + (k-1)]);
    lds_order();
    #pragma unroll
    for (int k1 = 0; k1 < 8; ++k1) sc[k1*72 + role] = v[k1];
    lds_order();
    // ---- stage 2: 8 independent 64-pt FFTs; radix-8 over stride 8 ----
    const int k1 = lane >> 3, m2 = lane & 7;
    float2 u[8];
    #pragma unroll
    for (int m1 = 0; m1 < 8; ++m1) u[m1] = sc[k1*72 + 8*m1 + m2];
    fft8(u);
    #pragma unroll
    for (int j = 1; j < 8; ++j) u[j] = cmul(u[j], tw2[j]);
    lds_order();
    #pragma unroll
    for (int j1 = 0; j1 < 8; ++j1) sc[k1*72 + 9*j1 + m2] = u[j1];
    lds_order();
    // ---- stage 3: radix-8 over stride 1, no twiddle ----
    const int j1 = lane & 7;
    #pragma unroll
    for (int m = 0; m < 8; ++m) v[m] = sc[k1*72 + 9*j1 + m];
    fft8(v);                         // v[j2] = X[k1 + 8*j1 + 64*j2]
}

// address-space typedefs for global_load_lds
using gu32 = __attribute__((address_space(1))) const unsigned int;
using lu32 = __attribute__((address_space(3))) unsigned int;

__global__ __launch_bounds__(256, 4) void sgn_fft_vec(
    const float* __restrict__ x,
    const float* __restrict__ cw,    // (H,L,512,2)
    float* __restrict__ out)
{
    __shared__ __align__(16) float2 sc[4][8*72];   // per-wave FFT + staging scratch (18432 B)
    __shared__ __align__(16) float  cwb[4][1024];  // per-wave DMA'd gate row (16384 B)
    __shared__ __align__(16) float2 twA[64*7];     // stage-1 twiddles (3584 B)

    const int tid  = threadIdx.x;
    const int wid  = tid >> 6;       // wave id in [0,4): packed pair (batches wid, wid+4)
    const int lane = tid & 63;
    const int dsl  = ((lane & 7) << 3) | (lane >> 3);
    const int hl   = blockIdx.x;     // weight row

    const int r1 = (wid       * HL + hl) * 512;   // batch wid
    const int r2 = ((wid + 4) * HL + hl) * 512;   // batch wid+4

    // ---- 1. cw row DMA: first instructions issued; lands during FFT1 ----
    {
        const float* cwrow = cw + (size_t)hl * 1024;
        #pragma unroll
        for (int c = 0; c < 4; ++c) {
            __builtin_amdgcn_global_load_lds((gu32*)(cwrow + c*256 + lane*4),
                                             (lu32*)(&cwb[wid][c*256]), 16, 0, 0);
        }
    }

    // ---- 2. x loads: 4 x dwordx4, lane-contiguous ----
    const float4 a0 = *(const float4*)(x + r1 + 4*lane);
    const float4 a1 = *(const float4*)(x + r1 + 4*lane + 256);
    const float4 b0 = *(const float4*)(x + r2 + 4*lane);
    const float4 b1 = *(const float4*)(x + r2 + 4*lane + 256);

    // ---- build stage-1 twiddle table (once per block); covers x-load latency ----
    {
        const int role = tid & 63, j = tid >> 6;     // j in [0,4)
        twA[role*7 + 2*j] = twiddle((float)(role*(2*j+1)) * (1.0f/512.0f));
        if (j < 3)
            twA[role*7 + 2*j + 1] = twiddle((float)(role*(2*j+2)) * (1.0f/512.0f));
    }
    // stage-2 twiddles in registers (lane&7 only, shared by both fft512 calls)
    float2 tw2[8];
    {
        const int m2 = lane & 7;
        tw2[1] = twiddle((float)m2 * (1.0f/64.0f));
        tw2[2] = cmul(tw2[1], tw2[1]);
        tw2[3] = cmul(tw2[1], tw2[2]);
        tw2[4] = cmul(tw2[2], tw2[2]);
        tw2[5] = cmul(tw2[1], tw2[4]);
        tw2[6] = cmul(tw2[2], tw2[4]);
        tw2[7] = cmul(tw2[3], tw2[4]);
    }
    __syncthreads();                 // twA visible to all waves

    float2* scw = &sc[wid][0];

    // ---- 3. stage x through sc: interleave (x1,x2) pairs AB[n]=(x1[n],x2[n]) ----
    {
        float2* AB = scw;
        *(float4*)&AB[      4*lane    ] = make_float4(a0.x, b0.x, a0.y, b0.y);
        *(float4*)&AB[      4*lane + 2] = make_float4(a0.z, b0.z, a0.w, b0.w);
        *(float4*)&AB[256 + 4*lane    ] = make_float4(a1.x, b1.x, a1.y, b1.y);
        *(float4*)&AB[256 + 4*lane + 2] = make_float4(a1.z, b1.z, a1.w, b1.w);
    }
    lds_order();
    // pack: z = x1 + i*x2, lane r holds z[64j + r]  (b64 reads, 4/bank = min)
    float2 v[8];
    #pragma unroll
    for (int j = 0; j < 8; ++j) v[j] = scw[64*j + lane];
    lds_order();                     // staging reads done before FFT1 overwrites sc

    fft512_t(v, lane, lane, scw, twA, tw2);

    // ---- 4. gate from LDS: G = Wp * Z (Wp pre-scaled by 1/512), then conj ----
    asm volatile("s_waitcnt vmcnt(0)" ::: "memory");   // cw DMA landed
    {
        const float2* __restrict__ cwf = (const float2*)&cwb[wid][0];
        const float hs = 0.5f / 512.0f;
        #pragma unroll
        for (int j2 = 0; j2 < 8; ++j2) {
            const int k  = dsl + 64*j2;
            const int nk = (512 - k) & 511;
            const float2 wk  = cwf[k];
            const float2 wnk = cwf[nk];
            const float2 wp  = make_float2(hs*(wk.x + wnk.x), hs*(wk.y - wnk.y));
            const float2 g   = cmul(wp, v[j2]);
            v[j2] = make_float2(g.x, -g.y);
        }
    }

    fft512_t(v, dsl, lane, scw, twA, tw2);

    // ---- 5. output restage: OD[k]=(out1[k],out2[k]) -> 4 dwordx4 stores ----
    lds_order();                     // FFT2 stage-3 sc reads drained (in-order)
    {
        float2* OD = scw;
        #pragma unroll
        for (int j2 = 0; j2 < 8; ++j2)
            OD[dsl + 64*j2] = make_float2(v[j2].x, -v[j2].y);   // b64, 4/bank = min
    }
    lds_order();
    #pragma unroll
    for (int c = 0; c < 2; ++c) {
        const float2* OD = scw;
        const float4 p = *(const float4*)&OD[4*lane + 256*c];
        const float4 q = *(const float4*)&OD[4*lane + 256*c + 2];
        *(float4*)(out + r1 + 4*lane + 256*c) = make_float4(p.x, p.z, q.x, q.z);
        *(float4*)(out + r2 + 4*lane + 256*c) = make_float4(p.y, p.w, q.y, q.w);
    }
}

extern "C" void kernel_launch(void* const* d_in, const int* in_sizes, int n_in,
                              void* d_out, int out_size, void* d_ws, size_t ws_size,
                              hipStream_t stream) {
    const float* x  = (const float*)d_in[0];   // (B,H,L,D) fp32
    // d_in[1] = mask, unused
    const float* cw = (const float*)d_in[2];   // (H,L,D,2) fp32
    float* out = (float*)d_out;

    sgn_fft_vec<<<dim3(HL), dim3(256), 0, stream>>>(x, cw, out);
}